// Round 1
// baseline (745.868 us; speedup 1.0000x reference)
//
#include <hip/hip_runtime.h>
#include <math.h>

#define HH 512
#define WW 512
#define NIMG 8
#define NPIX (NIMG * HH * WW)
#define GAMMA_FLOW 0.001f
#define GAMMA_MASK 0.0005f
#define INV_TOTAL (1.0f / (float)(NPIX * 3))

// ---------------- K1: 3x3x32->3 conv + tanh ----------------
// 1 pixel/thread. Weight indices are compile-time constants after full
// unroll -> uniform address -> compiler emits scalar loads (K$-cached).
__global__ __launch_bounds__(256) void conv_tanh_kernel(
    const float* __restrict__ enc, const float* __restrict__ cw,
    const float* __restrict__ cb, float* __restrict__ flow,
    float* __restrict__ mask)
{
    int idx = blockIdx.x * 256 + threadIdx.x;
    int w = idx & (WW - 1);
    int h = (idx >> 9) & (HH - 1);

    float a0 = cb[0], a1 = cb[1], a2 = cb[2];

#pragma unroll
    for (int kh = 0; kh < 3; ++kh) {
        int hr = h + kh - 1;
        if ((unsigned)hr >= (unsigned)HH) continue;  // zero pad
#pragma unroll
        for (int kw = 0; kw < 3; ++kw) {
            int wc = w + kw - 1;
            if ((unsigned)wc >= (unsigned)WW) continue;  // zero pad
            const float* p = enc + (size_t)(idx + (kh - 1) * WW + (kw - 1)) * 32;
            const float* wp = cw + (size_t)((kh * 3 + kw) * 32) * 3;
#pragma unroll
            for (int c4 = 0; c4 < 8; ++c4) {
                float4 v = *reinterpret_cast<const float4*>(p + c4 * 4);
                int cb0 = (c4 * 4) * 3;
                a0 = fmaf(v.x, wp[cb0 + 0], a0);
                a1 = fmaf(v.x, wp[cb0 + 1], a1);
                a2 = fmaf(v.x, wp[cb0 + 2], a2);
                a0 = fmaf(v.y, wp[cb0 + 3], a0);
                a1 = fmaf(v.y, wp[cb0 + 4], a1);
                a2 = fmaf(v.y, wp[cb0 + 5], a2);
                a0 = fmaf(v.z, wp[cb0 + 6], a0);
                a1 = fmaf(v.z, wp[cb0 + 7], a1);
                a2 = fmaf(v.z, wp[cb0 + 8], a2);
                a0 = fmaf(v.w, wp[cb0 + 9], a0);
                a1 = fmaf(v.w, wp[cb0 + 10], a1);
                a2 = fmaf(v.w, wp[cb0 + 11], a2);
            }
        }
    }

    flow[(size_t)idx * 2 + 0] = tanhf(a0);
    flow[(size_t)idx * 2 + 1] = tanhf(a1);
    mask[idx] = tanhf(a2);
}

// ---------------- K2: bilinear warp + blend + TV ----------------
// Replicates reference semantics exactly:
//   hp = (coor+1)*(H-1)/2 ; h0 = floor(hp) ; h1 = clip(h0+1) (from UNclipped
//   h0) ; h0 = clip(h0) ; weights from (h1f - hp) with clipped h1 as float.
__device__ __forceinline__ void bilerp3(const float* __restrict__ img,
                                        float ch, float cwv, float out[3])
{
    float hp = (ch + 1.0f) * 255.5f;   // (H-1)/2 = 255.5 exact
    float wp = (cwv + 1.0f) * 255.5f;
    int h0 = (int)floorf(hp);
    int w0 = (int)floorf(wp);
    int h1 = min(max(h0 + 1, 0), HH - 1);
    int w1 = min(max(w0 + 1, 0), WW - 1);
    int h0c = min(max(h0, 0), HH - 1);
    int w0c = min(max(w0, 0), WW - 1);
    float wh = (float)h1 - hp;
    float wv = (float)w1 - wp;
    float w_ru = wh * wv;
    float w_rd = (1.0f - wh) * wv;
    float w_lu = wh * (1.0f - wv);
    float w_ld = (1.0f - wh) * (1.0f - wv);
    const float* pru = img + (size_t)((h0c << 9) + w0c) * 6;
    const float* prd = img + (size_t)((h1 << 9) + w0c) * 6;
    const float* plu = img + (size_t)((h0c << 9) + w1) * 6;
    const float* pld = img + (size_t)((h1 << 9) + w1) * 6;
#pragma unroll
    for (int c = 0; c < 3; ++c) {
        out[c] = w_ru * pru[c] + w_rd * prd[c] + w_lu * plu[c] + w_ld * pld[c];
    }
}

__global__ __launch_bounds__(256) void interp_tv_kernel(
    const float* __restrict__ frames, const float* __restrict__ flow,
    const float* __restrict__ mask, float* __restrict__ stacked,
    float* __restrict__ tv_out)
{
    int idx = blockIdx.x * 256 + threadIdx.x;
    int w = idx & (WW - 1);
    int h = (idx >> 9) & (HH - 1);
    int n = idx >> 18;

    float f0 = flow[(size_t)idx * 2 + 0];
    float f1 = flow[(size_t)idx * 2 + 1];
    float mk = mask[idx];

    float hh = -1.0f + (float)h * (2.0f / 511.0f);
    float wwv = -1.0f + (float)w * (2.0f / 511.0f);

    const float* img = frames + (size_t)n * (HH * WW * 6);

    float o0[3], o1[3];
    // frame0 warped by +0.5*flow
    bilerp3(img + 0, hh + f0 * 0.5f, wwv + f1 * 0.5f, o0);
    // frame1 warped by -0.5*flow
    bilerp3(img + 3, hh - f0 * 0.5f, wwv - f1 * 0.5f, o1);

    float m = 0.5f * (1.0f + mk);
    float om = 1.0f - m;
#pragma unroll
    for (int c = 0; c < 3; ++c) {
        stacked[(size_t)idx * 3 + c] = m * o0[c] + om * o1[c];
    }

    // --- TV partial (down- and right-neighbor diffs) ---
    float tv = 0.0f;
    if (h < HH - 1) {
        float f0d = flow[(size_t)(idx + WW) * 2 + 0];
        float f1d = flow[(size_t)(idx + WW) * 2 + 1];
        float md = mask[idx + WW];
        tv += GAMMA_FLOW * (fabsf(f0d - f0) + fabsf(f1d - f1))
            + GAMMA_MASK * fabsf(md - mk);
    }
    if (w < WW - 1) {
        float f0r = flow[(size_t)(idx + 1) * 2 + 0];
        float f1r = flow[(size_t)(idx + 1) * 2 + 1];
        float mr = mask[idx + 1];
        tv += GAMMA_FLOW * (fabsf(f0r - f0) + fabsf(f1r - f1))
            + GAMMA_MASK * fabsf(mr - mk);
    }

    // wave-64 butterfly reduce, one atomic per wave
#pragma unroll
    for (int off = 32; off > 0; off >>= 1) {
        tv += __shfl_xor(tv, off, 64);
    }
    if ((threadIdx.x & 63) == 0) {
        atomicAdd(tv_out, tv * INV_TOTAL);
    }
}

extern "C" void kernel_launch(void* const* d_in, const int* in_sizes, int n_in,
                              void* d_out, int out_size, void* d_ws, size_t ws_size,
                              hipStream_t stream)
{
    const float* frames  = (const float*)d_in[0];
    const float* encoded = (const float*)d_in[1];
    const float* conv_w  = (const float*)d_in[2];
    const float* conv_b  = (const float*)d_in[3];

    float* out = (float*)d_out;
    float* stacked = out;                           // NPIX*3
    float* flow    = out + (size_t)NPIX * 3;        // NPIX*2
    float* tv      = out + (size_t)NPIX * 5;        // 1

    float* mask = (float*)d_ws;                     // NPIX floats scratch

    hipMemsetAsync(tv, 0, sizeof(float), stream);

    int blocks = NPIX / 256;
    conv_tanh_kernel<<<blocks, 256, 0, stream>>>(encoded, conv_w, conv_b,
                                                 flow, mask);
    interp_tv_kernel<<<blocks, 256, 0, stream>>>(frames, flow, mask,
                                                 stacked, tv);
}

// Round 2
// 744.636 us; speedup vs baseline: 1.0017x; 1.0017x over previous
//
#include <hip/hip_runtime.h>
#include <hip/hip_fp16.h>
#include <math.h>

#define HH 512
#define WW 512
#define NIMG 8
#define NPIX (NIMG * HH * WW)          // 2,097,152
#define GAMMA_FLOW 0.001f
#define GAMMA_MASK 0.0005f
#define INV_TOTAL (1.0f / (float)(NPIX * 3))

// ================= K0: frames fp32 NHWC(6) -> two planar fp16 (padded 4/px) ==
__global__ __launch_bounds__(256) void cvt_kernel(
    const float* __restrict__ frames,
    __half* __restrict__ f0h, __half* __restrict__ f1h)
{
    int t = blockIdx.x * 256 + threadIdx.x;            // one pixel
    const float2* fp = reinterpret_cast<const float2*>(frames + (size_t)t * 6);
    float2 v0 = fp[0], v1 = fp[1], v2 = fp[2];
    __half2 a = __floats2half2_rn(v0.x, v0.y);         // f0 ch0,ch1
    __half2 b = __floats2half2_rn(v1.x, 0.0f);         // f0 ch2, pad
    __half2 c = __floats2half2_rn(v1.y, v2.x);         // f1 ch0,ch1
    __half2 d = __floats2half2_rn(v2.y, 0.0f);         // f1 ch2, pad
    __half2* p0 = reinterpret_cast<__half2*>(f0h) + (size_t)t * 2;
    __half2* p1 = reinterpret_cast<__half2*>(f1h) + (size_t)t * 2;
    p0[0] = a; p0[1] = b;
    p1[0] = c; p1[1] = d;
}

// ================= K1: 3x3x32->3 conv + tanh (lane = 8px x 8ch-chunks) ======
// Block = one image row (512 px) = 4 waves x 128 px. Wave iter = 8 px.
// Lane (p3 = lane>>3 pixel, c4 = lane&7 channel-chunk of 4). Coalesced 1KB
// loads; 3-step shfl_xor reduce over c4; bias+tanh after reduce.
__global__ __launch_bounds__(256) void conv_tanh_kernel(
    const float* __restrict__ enc, const float* __restrict__ cw,
    const float* __restrict__ cb, float* __restrict__ flow,
    float* __restrict__ mask)
{
    int bid = blockIdx.x;
    int wb  = (bid & 7) * (NIMG * HH / 8) + (bid >> 3); // XCD k <- image k
    int n = wb >> 9;
    int h = wb & (HH - 1);

    int tid  = threadIdx.x;
    int wv   = tid >> 6;
    int lane = tid & 63;
    int p3   = lane >> 3;
    int c4   = lane & 7;

    // per-lane weights: 9 taps x (4 ch x 3 out) = 27 float4
    float4 wt[9][3];
    const float4* cw4 = reinterpret_cast<const float4*>(cw);
#pragma unroll
    for (int t = 0; t < 9; ++t) {
        int fi = t * 24 + c4 * 3;        // ((t*32 + c4*4)*3)/4
        wt[t][0] = cw4[fi + 0];
        wt[t][1] = cw4[fi + 1];
        wt[t][2] = cw4[fi + 2];
    }
    float b0 = cb[0], b1 = cb[1], b2 = cb[2];

    int wseg = wv * 128;
    const size_t row_base = (size_t)(n * HH);

#pragma unroll 2
    for (int it = 0; it < 16; ++it) {
        int w0 = wseg + it * 8 + p3;
        float a0 = 0.0f, a1 = 0.0f, a2 = 0.0f;
#pragma unroll
        for (int kh = 0; kh < 3; ++kh) {
            int hr = h + kh - 1;
            if ((unsigned)hr >= (unsigned)HH) continue;   // uniform branch
#pragma unroll
            for (int kw = 0; kw < 3; ++kw) {
                int wc = w0 + kw - 1;
                float4 x = make_float4(0.f, 0.f, 0.f, 0.f);
                if ((unsigned)wc < (unsigned)WW) {
                    x = *(reinterpret_cast<const float4*>(
                            enc + ((row_base + hr) * WW + wc) * 32) + c4);
                }
                const float* wf = reinterpret_cast<const float*>(&wt[kh * 3 + kw][0]);
                float xv[4] = {x.x, x.y, x.z, x.w};
#pragma unroll
                for (int k = 0; k < 4; ++k) {
                    a0 = fmaf(xv[k], wf[k * 3 + 0], a0);
                    a1 = fmaf(xv[k], wf[k * 3 + 1], a1);
                    a2 = fmaf(xv[k], wf[k * 3 + 2], a2);
                }
            }
        }
        // reduce over 8 channel-chunk lanes (xor 1,2,4 stays in-group)
#pragma unroll
        for (int off = 1; off < 8; off <<= 1) {
            a0 += __shfl_xor(a0, off);
            a1 += __shfl_xor(a1, off);
            a2 += __shfl_xor(a2, off);
        }
        float t0 = tanhf(a0 + b0);
        float t1 = tanhf(a1 + b1);
        float t2 = tanhf(a2 + b2);
        if (c4 == 0) {
            size_t idx = (row_base + h) * WW + w0;
            *reinterpret_cast<float2*>(flow + idx * 2) = make_float2(t0, t1);
            mask[idx] = t2;
        }
    }
}

// ================= K2: bilinear warp + blend + TV ===========================
__device__ __forceinline__ void bilerp_h(const __half* __restrict__ img,
                                         float ch, float cwv, float out[3])
{
    float hp = (ch + 1.0f) * 255.5f;
    float wp = (cwv + 1.0f) * 255.5f;
    int h0 = (int)floorf(hp);
    int w0 = (int)floorf(wp);
    int h1  = min(max(h0 + 1, 0), HH - 1);
    int w1  = min(max(w0 + 1, 0), WW - 1);
    int h0c = min(max(h0, 0), HH - 1);
    int w0c = min(max(w0, 0), WW - 1);
    float wh = (float)h1 - hp;
    float wv = (float)w1 - wp;
    float w_ru = wh * wv;
    float w_rd = (1.0f - wh) * wv;
    float w_lu = wh * (1.0f - wv);
    float w_ld = (1.0f - wh) * (1.0f - wv);
    const __half2* pru = reinterpret_cast<const __half2*>(img) + ((h0c << 9) + w0c) * 2;
    const __half2* prd = reinterpret_cast<const __half2*>(img) + ((h1  << 9) + w0c) * 2;
    const __half2* plu = reinterpret_cast<const __half2*>(img) + ((h0c << 9) + w1) * 2;
    const __half2* pld = reinterpret_cast<const __half2*>(img) + ((h1  << 9) + w1) * 2;
    __half2 ru0 = pru[0], ru1 = pru[1];
    __half2 rd0 = prd[0], rd1 = prd[1];
    __half2 lu0 = plu[0], lu1 = plu[1];
    __half2 ld0 = pld[0], ld1 = pld[1];
    float2 ruA = __half22float2(ru0); float ruZ = __half2float(ru1.x);
    float2 rdA = __half22float2(rd0); float rdZ = __half2float(rd1.x);
    float2 luA = __half22float2(lu0); float luZ = __half2float(lu1.x);
    float2 ldA = __half22float2(ld0); float ldZ = __half2float(ld1.x);
    out[0] = w_ru * ruA.x + w_rd * rdA.x + w_lu * luA.x + w_ld * ldA.x;
    out[1] = w_ru * ruA.y + w_rd * rdA.y + w_lu * luA.y + w_ld * ldA.y;
    out[2] = w_ru * ruZ   + w_rd * rdZ   + w_lu * luZ   + w_ld * ldZ;
}

__device__ __forceinline__ void bilerp_f(const float* __restrict__ img,
                                         float ch, float cwv, float out[3])
{
    float hp = (ch + 1.0f) * 255.5f;
    float wp = (cwv + 1.0f) * 255.5f;
    int h0 = (int)floorf(hp);
    int w0 = (int)floorf(wp);
    int h1  = min(max(h0 + 1, 0), HH - 1);
    int w1  = min(max(w0 + 1, 0), WW - 1);
    int h0c = min(max(h0, 0), HH - 1);
    int w0c = min(max(w0, 0), WW - 1);
    float wh = (float)h1 - hp;
    float wv = (float)w1 - wp;
    float w_ru = wh * wv;
    float w_rd = (1.0f - wh) * wv;
    float w_lu = wh * (1.0f - wv);
    float w_ld = (1.0f - wh) * (1.0f - wv);
    const float* pru = img + (size_t)((h0c << 9) + w0c) * 6;
    const float* prd = img + (size_t)((h1  << 9) + w0c) * 6;
    const float* plu = img + (size_t)((h0c << 9) + w1) * 6;
    const float* pld = img + (size_t)((h1  << 9) + w1) * 6;
#pragma unroll
    for (int c = 0; c < 3; ++c)
        out[c] = w_ru * pru[c] + w_rd * prd[c] + w_lu * plu[c] + w_ld * pld[c];
}

// MODE 0: fp16 planar padded frames (f0h/f1h). MODE 1: direct fp32 frames.
template<int MODE>
__global__ __launch_bounds__(256) void interp_tv_kernel(
    const float* __restrict__ frames,
    const __half* __restrict__ f0h, const __half* __restrict__ f1h,
    const float* __restrict__ flow, const float* __restrict__ mask,
    float* __restrict__ stacked, float* __restrict__ tv_out)
{
    int bid = blockIdx.x;
    int wb  = (bid & 7) * (NPIX / 512 / 8) + (bid >> 3);  // image n -> XCD n
    int idx0 = wb * 512 + (int)threadIdx.x * 2;           // 2 adjacent px
    int w0 = idx0 & (WW - 1);
    int h  = (idx0 >> 9) & (HH - 1);
    int n  = idx0 >> 18;

    float4 fl = *reinterpret_cast<const float4*>(flow + (size_t)idx0 * 2);
    float2 mk = *reinterpret_cast<const float2*>(mask + idx0);

    float hhv = -1.0f + (float)h * (2.0f / 511.0f);
    float wv0 = -1.0f + (float)w0 * (2.0f / 511.0f);
    float wv1 = -1.0f + (float)(w0 + 1) * (2.0f / 511.0f);

    float o00[3], o01[3], o10[3], o11[3];
    if constexpr (MODE == 0) {
        const __half* i0 = f0h + (size_t)n * (HH * WW * 4);
        const __half* i1 = f1h + (size_t)n * (HH * WW * 4);
        bilerp_h(i0, hhv + fl.x * 0.5f, wv0 + fl.y * 0.5f, o00);
        bilerp_h(i1, hhv - fl.x * 0.5f, wv0 - fl.y * 0.5f, o01);
        bilerp_h(i0, hhv + fl.z * 0.5f, wv1 + fl.w * 0.5f, o10);
        bilerp_h(i1, hhv - fl.z * 0.5f, wv1 - fl.w * 0.5f, o11);
    } else {
        const float* img = frames + (size_t)n * (HH * WW * 6);
        bilerp_f(img + 0, hhv + fl.x * 0.5f, wv0 + fl.y * 0.5f, o00);
        bilerp_f(img + 3, hhv - fl.x * 0.5f, wv0 - fl.y * 0.5f, o01);
        bilerp_f(img + 0, hhv + fl.z * 0.5f, wv1 + fl.w * 0.5f, o10);
        bilerp_f(img + 3, hhv - fl.z * 0.5f, wv1 - fl.w * 0.5f, o11);
    }

    float m0 = 0.5f * (1.0f + mk.x), om0 = 1.0f - m0;
    float m1 = 0.5f * (1.0f + mk.y), om1 = 1.0f - m1;
    float2* sp = reinterpret_cast<float2*>(stacked + (size_t)idx0 * 3);
    sp[0] = make_float2(m0 * o00[0] + om0 * o01[0], m0 * o00[1] + om0 * o01[1]);
    sp[1] = make_float2(m0 * o00[2] + om0 * o01[2], m1 * o10[0] + om1 * o11[0]);
    sp[2] = make_float2(m1 * o10[1] + om1 * o11[1], m1 * o10[2] + om1 * o11[2]);

    // ---- TV (right diff for px0 is in-register) ----
    float tvf = fabsf(fl.z - fl.x) + fabsf(fl.w - fl.y);
    float tvm = fabsf(mk.y - mk.x);
    if (h < HH - 1) {
        float4 fld = *reinterpret_cast<const float4*>(flow + (size_t)(idx0 + WW) * 2);
        float2 mkd = *reinterpret_cast<const float2*>(mask + (idx0 + WW));
        tvf += fabsf(fld.x - fl.x) + fabsf(fld.y - fl.y)
             + fabsf(fld.z - fl.z) + fabsf(fld.w - fl.w);
        tvm += fabsf(mkd.x - mk.x) + fabsf(mkd.y - mk.y);
    }
    if (w0 < WW - 2) {
        float2 flr = *reinterpret_cast<const float2*>(flow + (size_t)(idx0 + 2) * 2);
        float  mkr = mask[idx0 + 2];
        tvf += fabsf(flr.x - fl.z) + fabsf(flr.y - fl.w);
        tvm += fabsf(mkr - mk.y);
    }
    float tv = GAMMA_FLOW * tvf + GAMMA_MASK * tvm;
#pragma unroll
    for (int off = 32; off > 0; off >>= 1) tv += __shfl_xor(tv, off);
    if ((threadIdx.x & 63) == 0) atomicAdd(tv_out, tv * INV_TOTAL);
}

extern "C" void kernel_launch(void* const* d_in, const int* in_sizes, int n_in,
                              void* d_out, int out_size, void* d_ws, size_t ws_size,
                              hipStream_t stream)
{
    const float* frames  = (const float*)d_in[0];
    const float* encoded = (const float*)d_in[1];
    const float* conv_w  = (const float*)d_in[2];
    const float* conv_b  = (const float*)d_in[3];

    float* out     = (float*)d_out;
    float* stacked = out;                       // NPIX*3
    float* flow    = out + (size_t)NPIX * 3;    // NPIX*2
    float* tv      = out + (size_t)NPIX * 5;    // 1

    hipMemsetAsync(tv, 0, sizeof(float), stream);

    const size_t frame_bytes = (size_t)NPIX * 4 * sizeof(__half); // 16 MiB each
    const size_t need = 2 * frame_bytes + (size_t)NPIX * sizeof(float);

    if (ws_size >= need) {
        __half* f0h = (__half*)d_ws;
        __half* f1h = (__half*)((char*)d_ws + frame_bytes);
        float*  mask = (float*)((char*)d_ws + 2 * frame_bytes);

        cvt_kernel<<<NPIX / 256, 256, 0, stream>>>(frames, f0h, f1h);
        conv_tanh_kernel<<<NIMG * HH, 256, 0, stream>>>(encoded, conv_w, conv_b,
                                                        flow, mask);
        interp_tv_kernel<0><<<NPIX / 512, 256, 0, stream>>>(
            frames, f0h, f1h, flow, mask, stacked, tv);
    } else {
        float* mask = (float*)d_ws;
        conv_tanh_kernel<<<NIMG * HH, 256, 0, stream>>>(encoded, conv_w, conv_b,
                                                        flow, mask);
        interp_tv_kernel<1><<<NPIX / 512, 256, 0, stream>>>(
            frames, (const __half*)nullptr, (const __half*)nullptr,
            flow, mask, stacked, tv);
    }
}

// Round 3
// 518.930 us; speedup vs baseline: 1.4373x; 1.4349x over previous
//
#include <hip/hip_runtime.h>
#include <hip/hip_fp16.h>
#include <math.h>

#define HH 512
#define WW 512
#define NIMG 8
#define NPIX (NIMG * HH * WW)          // 2,097,152
#define GAMMA_FLOW 0.001f
#define GAMMA_MASK 0.0005f
#define INV_TOTAL (1.0f / (float)(NPIX * 3))

__device__ __forceinline__ float tanh_fast(float x)
{
    // 1 - 2/(exp(2x)+1): exact at saturation (inf -> 1, 0 -> -1), ~1e-6 err
    float e = __expf(2.0f * x);
    return 1.0f - 2.0f / (e + 1.0f);
}

// ================= K0: frames fp32 NHWC(6) -> two planar fp16 (padded 4/px) ==
__global__ __launch_bounds__(256) void cvt_kernel(
    const float* __restrict__ frames,
    __half* __restrict__ f0h, __half* __restrict__ f1h)
{
    int t = blockIdx.x * 256 + threadIdx.x;            // one pixel
    const float2* fp = reinterpret_cast<const float2*>(frames + (size_t)t * 6);
    float2 v0 = fp[0], v1 = fp[1], v2 = fp[2];
    __half2 a = __floats2half2_rn(v0.x, v0.y);         // f0 ch0,ch1
    __half2 b = __floats2half2_rn(v1.x, 0.0f);         // f0 ch2, pad
    __half2 c = __floats2half2_rn(v1.y, v2.x);         // f1 ch0,ch1
    __half2 d = __floats2half2_rn(v2.y, 0.0f);         // f1 ch2, pad
    __half2* p0 = reinterpret_cast<__half2*>(f0h) + (size_t)t * 2;
    __half2* p1 = reinterpret_cast<__half2*>(f1h) + (size_t)t * 2;
    p0[0] = a; p0[1] = b;
    p1[0] = c; p1[1] = d;
}

// ================= K1: 3x3x32->3 conv + tanh =================================
// Tap-outer / pixel-group-inner: only ONE tap's weights (12 floats) live at a
// time -> no spill (r2 held all 27 float4 -> 108 VGPR -> spilled, 546us).
// Wave = 32 px as 4 groups x (8 px x 8 ch-chunks). Block = 4 waves = 128 px.
// Enc loads are 1KB/instruction coalesced; 3-step shfl_xor reduce over c4.
__global__ __launch_bounds__(256) void conv_tanh_kernel(
    const float* __restrict__ enc, const float* __restrict__ cw,
    const float* __restrict__ cb, float* __restrict__ flow,
    float* __restrict__ mask)
{
    int bid = blockIdx.x;                        // 16384 blocks
    int wb  = (bid & 7) * (NPIX / 128 / 8) + (bid >> 3);  // image n -> XCD n
    int px0 = wb * 128;                          // block pixel base (one row)
    int n = px0 >> 18;
    int h = (px0 >> 9) & (HH - 1);

    int tid  = threadIdx.x;
    int wv   = tid >> 6;
    int lane = tid & 63;
    int p3   = lane >> 3;                        // pixel within group
    int c4   = lane & 7;                         // channel chunk (4 ch)

    int wbase = (px0 & (WW - 1)) + wv * 32;      // wave's 32-px segment
    int w0 = wbase + p3;                         // pg stride = 8

    const float4* cw4 = reinterpret_cast<const float4*>(cw);
    const float*  imgbase = enc + ((size_t)n * HH) * WW * 32;

    float acc[4][3];
#pragma unroll
    for (int pg = 0; pg < 4; ++pg)
        acc[pg][0] = acc[pg][1] = acc[pg][2] = 0.0f;

#pragma unroll
    for (int kh = 0; kh < 3; ++kh) {
        int hr = h + kh - 1;
        bool hok = (unsigned)hr < (unsigned)HH;  // zero pad (uniform)
        const float* rowp = imgbase + (size_t)hr * WW * 32;
#pragma unroll
        for (int kw = 0; kw < 3; ++kw) {
            int t = kh * 3 + kw;
            // this tap's 12 weights for chunk c4 (static-indexed -> registers)
            float wf[12];
            *reinterpret_cast<float4*>(&wf[0]) = cw4[t * 24 + c4 * 3 + 0];
            *reinterpret_cast<float4*>(&wf[4]) = cw4[t * 24 + c4 * 3 + 1];
            *reinterpret_cast<float4*>(&wf[8]) = cw4[t * 24 + c4 * 3 + 2];
#pragma unroll
            for (int pg = 0; pg < 4; ++pg) {
                int wc = w0 + pg * 8 + kw - 1;
                float4 x = make_float4(0.f, 0.f, 0.f, 0.f);
                if (hok && (unsigned)wc < (unsigned)WW) {
                    x = *(reinterpret_cast<const float4*>(rowp) + wc * 8 + c4);
                }
                float xv[4] = {x.x, x.y, x.z, x.w};
#pragma unroll
                for (int k = 0; k < 4; ++k) {
                    acc[pg][0] = fmaf(xv[k], wf[k * 3 + 0], acc[pg][0]);
                    acc[pg][1] = fmaf(xv[k], wf[k * 3 + 1], acc[pg][1]);
                    acc[pg][2] = fmaf(xv[k], wf[k * 3 + 2], acc[pg][2]);
                }
            }
        }
    }

    float b0 = cb[0], b1 = cb[1], b2 = cb[2];
    size_t rowidx = ((size_t)n * HH + h) * WW;

#pragma unroll
    for (int pg = 0; pg < 4; ++pg) {
        float a0 = acc[pg][0], a1 = acc[pg][1], a2 = acc[pg][2];
#pragma unroll
        for (int off = 1; off < 8; off <<= 1) {   // reduce over c4 lanes
            a0 += __shfl_xor(a0, off);
            a1 += __shfl_xor(a1, off);
            a2 += __shfl_xor(a2, off);
        }
        float t0 = tanh_fast(a0 + b0);
        float t1 = tanh_fast(a1 + b1);
        float t2 = tanh_fast(a2 + b2);
        if (c4 == 0) {
            size_t idx = rowidx + (size_t)(w0 + pg * 8);
            *reinterpret_cast<float2*>(flow + idx * 2) = make_float2(t0, t1);
            mask[idx] = t2;
        }
    }
}

// ================= K2: bilinear warp + blend + TV ===========================
__device__ __forceinline__ void bilerp_h(const __half* __restrict__ img,
                                         float ch, float cwv, float out[3])
{
    float hp = (ch + 1.0f) * 255.5f;
    float wp = (cwv + 1.0f) * 255.5f;
    int h0 = (int)floorf(hp);
    int w0 = (int)floorf(wp);
    int h1  = min(max(h0 + 1, 0), HH - 1);
    int w1  = min(max(w0 + 1, 0), WW - 1);
    int h0c = min(max(h0, 0), HH - 1);
    int w0c = min(max(w0, 0), WW - 1);
    float wh = (float)h1 - hp;
    float wv = (float)w1 - wp;
    float w_ru = wh * wv;
    float w_rd = (1.0f - wh) * wv;
    float w_lu = wh * (1.0f - wv);
    float w_ld = (1.0f - wh) * (1.0f - wv);
    const __half2* pru = reinterpret_cast<const __half2*>(img) + ((h0c << 9) + w0c) * 2;
    const __half2* prd = reinterpret_cast<const __half2*>(img) + ((h1  << 9) + w0c) * 2;
    const __half2* plu = reinterpret_cast<const __half2*>(img) + ((h0c << 9) + w1) * 2;
    const __half2* pld = reinterpret_cast<const __half2*>(img) + ((h1  << 9) + w1) * 2;
    __half2 ru0 = pru[0], ru1 = pru[1];
    __half2 rd0 = prd[0], rd1 = prd[1];
    __half2 lu0 = plu[0], lu1 = plu[1];
    __half2 ld0 = pld[0], ld1 = pld[1];
    float2 ruA = __half22float2(ru0); float ruZ = __half2float(ru1.x);
    float2 rdA = __half22float2(rd0); float rdZ = __half2float(rd1.x);
    float2 luA = __half22float2(lu0); float luZ = __half2float(lu1.x);
    float2 ldA = __half22float2(ld0); float ldZ = __half2float(ld1.x);
    out[0] = w_ru * ruA.x + w_rd * rdA.x + w_lu * luA.x + w_ld * ldA.x;
    out[1] = w_ru * ruA.y + w_rd * rdA.y + w_lu * luA.y + w_ld * ldA.y;
    out[2] = w_ru * ruZ   + w_rd * rdZ   + w_lu * luZ   + w_ld * ldZ;
}

__device__ __forceinline__ void bilerp_f(const float* __restrict__ img,
                                         float ch, float cwv, float out[3])
{
    float hp = (ch + 1.0f) * 255.5f;
    float wp = (cwv + 1.0f) * 255.5f;
    int h0 = (int)floorf(hp);
    int w0 = (int)floorf(wp);
    int h1  = min(max(h0 + 1, 0), HH - 1);
    int w1  = min(max(w0 + 1, 0), WW - 1);
    int h0c = min(max(h0, 0), HH - 1);
    int w0c = min(max(w0, 0), WW - 1);
    float wh = (float)h1 - hp;
    float wv = (float)w1 - wp;
    float w_ru = wh * wv;
    float w_rd = (1.0f - wh) * wv;
    float w_lu = wh * (1.0f - wv);
    float w_ld = (1.0f - wh) * (1.0f - wv);
    const float* pru = img + (size_t)((h0c << 9) + w0c) * 6;
    const float* prd = img + (size_t)((h1  << 9) + w0c) * 6;
    const float* plu = img + (size_t)((h0c << 9) + w1) * 6;
    const float* pld = img + (size_t)((h1  << 9) + w1) * 6;
#pragma unroll
    for (int c = 0; c < 3; ++c)
        out[c] = w_ru * pru[c] + w_rd * prd[c] + w_lu * plu[c] + w_ld * pld[c];
}

// MODE 0: fp16 planar padded frames (f0h/f1h). MODE 1: direct fp32 frames.
template<int MODE>
__global__ __launch_bounds__(256) void interp_tv_kernel(
    const float* __restrict__ frames,
    const __half* __restrict__ f0h, const __half* __restrict__ f1h,
    const float* __restrict__ flow, const float* __restrict__ mask,
    float* __restrict__ stacked, float* __restrict__ tv_out)
{
    int bid = blockIdx.x;
    int wb  = (bid & 7) * (NPIX / 512 / 8) + (bid >> 3);  // image n -> XCD n
    int idx0 = wb * 512 + (int)threadIdx.x * 2;           // 2 adjacent px
    int w0 = idx0 & (WW - 1);
    int h  = (idx0 >> 9) & (HH - 1);
    int n  = idx0 >> 18;

    float4 fl = *reinterpret_cast<const float4*>(flow + (size_t)idx0 * 2);
    float2 mk = *reinterpret_cast<const float2*>(mask + idx0);

    float hhv = -1.0f + (float)h * (2.0f / 511.0f);
    float wv0 = -1.0f + (float)w0 * (2.0f / 511.0f);
    float wv1 = -1.0f + (float)(w0 + 1) * (2.0f / 511.0f);

    float o00[3], o01[3], o10[3], o11[3];
    if constexpr (MODE == 0) {
        const __half* i0 = f0h + (size_t)n * (HH * WW * 4);
        const __half* i1 = f1h + (size_t)n * (HH * WW * 4);
        bilerp_h(i0, hhv + fl.x * 0.5f, wv0 + fl.y * 0.5f, o00);
        bilerp_h(i1, hhv - fl.x * 0.5f, wv0 - fl.y * 0.5f, o01);
        bilerp_h(i0, hhv + fl.z * 0.5f, wv1 + fl.w * 0.5f, o10);
        bilerp_h(i1, hhv - fl.z * 0.5f, wv1 - fl.w * 0.5f, o11);
    } else {
        const float* img = frames + (size_t)n * (HH * WW * 6);
        bilerp_f(img + 0, hhv + fl.x * 0.5f, wv0 + fl.y * 0.5f, o00);
        bilerp_f(img + 3, hhv - fl.x * 0.5f, wv0 - fl.y * 0.5f, o01);
        bilerp_f(img + 0, hhv + fl.z * 0.5f, wv1 + fl.w * 0.5f, o10);
        bilerp_f(img + 3, hhv - fl.z * 0.5f, wv1 - fl.w * 0.5f, o11);
    }

    float m0 = 0.5f * (1.0f + mk.x), om0 = 1.0f - m0;
    float m1 = 0.5f * (1.0f + mk.y), om1 = 1.0f - m1;
    float2* sp = reinterpret_cast<float2*>(stacked + (size_t)idx0 * 3);
    sp[0] = make_float2(m0 * o00[0] + om0 * o01[0], m0 * o00[1] + om0 * o01[1]);
    sp[1] = make_float2(m0 * o00[2] + om0 * o01[2], m1 * o10[0] + om1 * o11[0]);
    sp[2] = make_float2(m1 * o10[1] + om1 * o11[1], m1 * o10[2] + om1 * o11[2]);

    // ---- TV (right diff for px0 is in-register) ----
    float tvf = fabsf(fl.z - fl.x) + fabsf(fl.w - fl.y);
    float tvm = fabsf(mk.y - mk.x);
    if (h < HH - 1) {
        float4 fld = *reinterpret_cast<const float4*>(flow + (size_t)(idx0 + WW) * 2);
        float2 mkd = *reinterpret_cast<const float2*>(mask + (idx0 + WW));
        tvf += fabsf(fld.x - fl.x) + fabsf(fld.y - fl.y)
             + fabsf(fld.z - fl.z) + fabsf(fld.w - fl.w);
        tvm += fabsf(mkd.x - mk.x) + fabsf(mkd.y - mk.y);
    }
    if (w0 < WW - 2) {
        float2 flr = *reinterpret_cast<const float2*>(flow + (size_t)(idx0 + 2) * 2);
        float  mkr = mask[idx0 + 2];
        tvf += fabsf(flr.x - fl.z) + fabsf(flr.y - fl.w);
        tvm += fabsf(mkr - mk.y);
    }
    float tv = GAMMA_FLOW * tvf + GAMMA_MASK * tvm;
#pragma unroll
    for (int off = 32; off > 0; off >>= 1) tv += __shfl_xor(tv, off);
    if ((threadIdx.x & 63) == 0) atomicAdd(tv_out, tv * INV_TOTAL);
}

extern "C" void kernel_launch(void* const* d_in, const int* in_sizes, int n_in,
                              void* d_out, int out_size, void* d_ws, size_t ws_size,
                              hipStream_t stream)
{
    const float* frames  = (const float*)d_in[0];
    const float* encoded = (const float*)d_in[1];
    const float* conv_w  = (const float*)d_in[2];
    const float* conv_b  = (const float*)d_in[3];

    float* out     = (float*)d_out;
    float* stacked = out;                       // NPIX*3
    float* flow    = out + (size_t)NPIX * 3;    // NPIX*2
    float* tv      = out + (size_t)NPIX * 5;    // 1

    hipMemsetAsync(tv, 0, sizeof(float), stream);

    const size_t frame_bytes = (size_t)NPIX * 4 * sizeof(__half); // 16 MiB each
    const size_t need = 2 * frame_bytes + (size_t)NPIX * sizeof(float);

    if (ws_size >= need) {
        __half* f0h = (__half*)d_ws;
        __half* f1h = (__half*)((char*)d_ws + frame_bytes);
        float*  mask = (float*)((char*)d_ws + 2 * frame_bytes);

        cvt_kernel<<<NPIX / 256, 256, 0, stream>>>(frames, f0h, f1h);
        conv_tanh_kernel<<<NPIX / 128, 256, 0, stream>>>(encoded, conv_w, conv_b,
                                                         flow, mask);
        interp_tv_kernel<0><<<NPIX / 512, 256, 0, stream>>>(
            frames, f0h, f1h, flow, mask, stacked, tv);
    } else {
        float* mask = (float*)d_ws;
        conv_tanh_kernel<<<NPIX / 128, 256, 0, stream>>>(encoded, conv_w, conv_b,
                                                         flow, mask);
        interp_tv_kernel<1><<<NPIX / 512, 256, 0, stream>>>(
            frames, (const __half*)nullptr, (const __half*)nullptr,
            flow, mask, stacked, tv);
    }
}

// Round 4
// 401.516 us; speedup vs baseline: 1.8576x; 1.2924x over previous
//
#include <hip/hip_runtime.h>
#include <hip/hip_fp16.h>
#include <math.h>

#define HH 512
#define WW 512
#define NIMG 8
#define NPIX (NIMG * HH * WW)          // 2,097,152
#define GAMMA_FLOW 0.001f
#define GAMMA_MASK 0.0005f
#define INV_TOTAL (1.0f / (float)(NPIX * 3))

__device__ __forceinline__ float tanh_fast(float x)
{
    float e = __expf(2.0f * x);
    return 1.0f - 2.0f / (e + 1.0f);
}

// ================= K0: frames fp32 NHWC(6) -> two planar fp16 (padded 4/px) ==
__global__ __launch_bounds__(256) void cvt_kernel(
    const float* __restrict__ frames,
    __half* __restrict__ f0h, __half* __restrict__ f1h)
{
    int t = blockIdx.x * 256 + threadIdx.x;            // one pixel
    const float2* fp = reinterpret_cast<const float2*>(frames + (size_t)t * 6);
    float2 v0 = fp[0], v1 = fp[1], v2 = fp[2];
    __half2 a = __floats2half2_rn(v0.x, v0.y);         // f0 ch0,ch1
    __half2 b = __floats2half2_rn(v1.x, 0.0f);         // f0 ch2, pad
    __half2 c = __floats2half2_rn(v1.y, v2.x);         // f1 ch0,ch1
    __half2 d = __floats2half2_rn(v2.y, 0.0f);         // f1 ch2, pad
    __half2* p0 = reinterpret_cast<__half2*>(f0h) + (size_t)t * 2;
    __half2* p1 = reinterpret_cast<__half2*>(f1h) + (size_t)t * 2;
    p0[0] = a; p0[1] = b;
    p1[0] = c; p1[1] = d;
}

// ================= K1: 3x3x32->3 conv + tanh =================================
// Wave = 32 px (4 pg x 8 px) x 8 ch-chunks. Per tap-row: ONE base address,
// 12 enc loads via immediate offsets ((pg*8+kw)*128B <= 3328 < 4096).
// Weights: one base (c4*48B), 27 imm-offset float4 loads. Bounds handling is
// a wave-uniform edge predicate (cols -1/512 only touch 2 of 16 waves/row).
// __launch_bounds__(256,4): VGPR<=128 (r3 was 136 -> 2 waves/SIMD cliff).
__device__ __forceinline__ void fma12(float acc[3], const float wf[12],
                                      float4 x)
{
    float xv[4] = {x.x, x.y, x.z, x.w};
#pragma unroll
    for (int k = 0; k < 4; ++k) {
        acc[0] = fmaf(xv[k], wf[k * 3 + 0], acc[0]);
        acc[1] = fmaf(xv[k], wf[k * 3 + 1], acc[1]);
        acc[2] = fmaf(xv[k], wf[k * 3 + 2], acc[2]);
    }
}

__global__ __launch_bounds__(256, 4) void conv_tanh_kernel(
    const float* __restrict__ enc, const float* __restrict__ cw,
    const float* __restrict__ cb, float* __restrict__ flow,
    float* __restrict__ mask)
{
    int bid = blockIdx.x;                                 // 16384 blocks
    int wb  = (bid & 7) * (NPIX / 128 / 8) + (bid >> 3);  // image n -> XCD n
    int px0 = wb * 128;
    int n = px0 >> 18;
    int h = (px0 >> 9) & (HH - 1);

    int tid  = threadIdx.x;
    int wv   = tid >> 6;
    int lane = tid & 63;
    int p3   = lane >> 3;                                 // pixel in group
    int c4   = lane & 7;                                  // channel chunk

    int wbase = (px0 & (WW - 1)) + wv * 32;               // wave's 32-px seg

    const float4* cwB = reinterpret_cast<const float4*>(cw) + c4 * 3;
    const float* imgbase = enc + ((size_t)n * HH) * (WW * 32);

    float acc[4][3];
#pragma unroll
    for (int pg = 0; pg < 4; ++pg)
        acc[pg][0] = acc[pg][1] = acc[pg][2] = 0.0f;

    bool edge = (wbase == 0) || (wbase == WW - 32);       // wave-uniform

    if (!edge) {
#pragma unroll
        for (int kh = 0; kh < 3; ++kh) {
            int hr = h + kh - 1;
            if ((unsigned)hr >= (unsigned)HH) continue;   // block-uniform
            const float* pB = imgbase + (size_t)hr * (WW * 32)
                            + (wbase - 1 + p3) * 32 + c4 * 4;
#pragma unroll
            for (int kw = 0; kw < 3; ++kw) {
                int t = kh * 3 + kw;
                float wf[12];
                *reinterpret_cast<float4*>(&wf[0]) = cwB[t * 24 + 0];
                *reinterpret_cast<float4*>(&wf[4]) = cwB[t * 24 + 1];
                *reinterpret_cast<float4*>(&wf[8]) = cwB[t * 24 + 2];
#pragma unroll
                for (int pg = 0; pg < 4; ++pg) {
                    float4 x = *reinterpret_cast<const float4*>(
                                   pB + (pg * 8 + kw) * 32);
                    fma12(acc[pg], wf, x);
                }
            }
        }
    } else {
#pragma unroll
        for (int kh = 0; kh < 3; ++kh) {
            int hr = h + kh - 1;
            if ((unsigned)hr >= (unsigned)HH) continue;
            const float* rowp = imgbase + (size_t)hr * (WW * 32);
#pragma unroll
            for (int kw = 0; kw < 3; ++kw) {
                int t = kh * 3 + kw;
                float wf[12];
                *reinterpret_cast<float4*>(&wf[0]) = cwB[t * 24 + 0];
                *reinterpret_cast<float4*>(&wf[4]) = cwB[t * 24 + 1];
                *reinterpret_cast<float4*>(&wf[8]) = cwB[t * 24 + 2];
#pragma unroll
                for (int pg = 0; pg < 4; ++pg) {
                    int wc = wbase + p3 + pg * 8 + kw - 1;
                    float4 x = make_float4(0.f, 0.f, 0.f, 0.f);
                    if ((unsigned)wc < (unsigned)WW)
                        x = *reinterpret_cast<const float4*>(
                                rowp + wc * 32 + c4 * 4);
                    fma12(acc[pg], wf, x);
                }
            }
        }
    }

    float b0 = cb[0], b1 = cb[1], b2 = cb[2];
    size_t rowidx = ((size_t)n * HH + h) * WW;

#pragma unroll
    for (int pg = 0; pg < 4; ++pg) {
        float a0 = acc[pg][0], a1 = acc[pg][1], a2 = acc[pg][2];
#pragma unroll
        for (int off = 1; off < 8; off <<= 1) {           // reduce over c4
            a0 += __shfl_xor(a0, off);
            a1 += __shfl_xor(a1, off);
            a2 += __shfl_xor(a2, off);
        }
        float t0 = tanh_fast(a0 + b0);
        float t1 = tanh_fast(a1 + b1);
        float t2 = tanh_fast(a2 + b2);
        if (c4 == 0) {
            size_t idx = rowidx + (size_t)(wbase + p3 + pg * 8);
            *reinterpret_cast<float2*>(flow + idx * 2) = make_float2(t0, t1);
            mask[idx] = t2;
        }
    }
}

// ================= K2: bilinear warp + blend + TV ===========================
// Pair-load: both w-corners of a row are adjacent 8B pixels -> one 16B load
// (8B-aligned) + cndmask selects for the clamp cases. Halves transactions.
__device__ __forceinline__ void bilerp_h(const __half* __restrict__ img,
                                         float ch, float cwv, float out[3])
{
    float hp = (ch + 1.0f) * 255.5f;
    float wp = (cwv + 1.0f) * 255.5f;
    int h0 = (int)floorf(hp);
    int w0 = (int)floorf(wp);
    int h1  = min(max(h0 + 1, 0), HH - 1);
    int w1  = min(max(w0 + 1, 0), WW - 1);
    int h0c = min(max(h0, 0), HH - 1);
    int w0c = min(max(w0, 0), WW - 1);
    float wh = (float)h1 - hp;
    float wv = (float)w1 - wp;
    float w_ru = wh * wv;
    float w_rd = (1.0f - wh) * wv;
    float w_lu = wh * (1.0f - wv);
    float w_ld = (1.0f - wh) * (1.0f - wv);

    int q = min(w0c, WW - 2);                 // pair base (pixels q, q+1)
    bool Ahi = (w0c != q);                    // w0c==511 -> hi pixel
    bool Bhi = (w1 == q + 1);
    float4 U = *reinterpret_cast<const float4*>(img + (size_t)(((h0c << 9) + q) << 2));
    float4 D = *reinterpret_cast<const float4*>(img + (size_t)(((h1  << 9) + q) << 2));
    // float4 = {px_q:ab, px_q:c_, px_q1:ab, px_q1:c_} (half2 bit-cast in floats)
    float ru_ab = Ahi ? U.z : U.x, ru_c = Ahi ? U.w : U.y;   // (h0c, w0c)
    float rd_ab = Ahi ? D.z : D.x, rd_c = Ahi ? D.w : D.y;   // (h1,  w0c)
    float lu_ab = Bhi ? U.z : U.x, lu_c = Bhi ? U.w : U.y;   // (h0c, w1)
    float ld_ab = Bhi ? D.z : D.x, ld_c = Bhi ? D.w : D.y;   // (h1,  w1)

    float2 ruA = __half22float2(*reinterpret_cast<__half2*>(&ru_ab));
    float2 rdA = __half22float2(*reinterpret_cast<__half2*>(&rd_ab));
    float2 luA = __half22float2(*reinterpret_cast<__half2*>(&lu_ab));
    float2 ldA = __half22float2(*reinterpret_cast<__half2*>(&ld_ab));
    float ruZ = __half2float(reinterpret_cast<__half2*>(&ru_c)->x);
    float rdZ = __half2float(reinterpret_cast<__half2*>(&rd_c)->x);
    float luZ = __half2float(reinterpret_cast<__half2*>(&lu_c)->x);
    float ldZ = __half2float(reinterpret_cast<__half2*>(&ld_c)->x);

    out[0] = w_ru * ruA.x + w_rd * rdA.x + w_lu * luA.x + w_ld * ldA.x;
    out[1] = w_ru * ruA.y + w_rd * rdA.y + w_lu * luA.y + w_ld * ldA.y;
    out[2] = w_ru * ruZ   + w_rd * rdZ   + w_lu * luZ   + w_ld * ldZ;
}

__device__ __forceinline__ void bilerp_f(const float* __restrict__ img,
                                         float ch, float cwv, float out[3])
{
    float hp = (ch + 1.0f) * 255.5f;
    float wp = (cwv + 1.0f) * 255.5f;
    int h0 = (int)floorf(hp);
    int w0 = (int)floorf(wp);
    int h1  = min(max(h0 + 1, 0), HH - 1);
    int w1  = min(max(w0 + 1, 0), WW - 1);
    int h0c = min(max(h0, 0), HH - 1);
    int w0c = min(max(w0, 0), WW - 1);
    float wh = (float)h1 - hp;
    float wv = (float)w1 - wp;
    float w_ru = wh * wv;
    float w_rd = (1.0f - wh) * wv;
    float w_lu = wh * (1.0f - wv);
    float w_ld = (1.0f - wh) * (1.0f - wv);
    const float* pru = img + (size_t)((h0c << 9) + w0c) * 6;
    const float* prd = img + (size_t)((h1  << 9) + w0c) * 6;
    const float* plu = img + (size_t)((h0c << 9) + w1) * 6;
    const float* pld = img + (size_t)((h1  << 9) + w1) * 6;
#pragma unroll
    for (int c = 0; c < 3; ++c)
        out[c] = w_ru * pru[c] + w_rd * prd[c] + w_lu * plu[c] + w_ld * pld[c];
}

// MODE 0: fp16 planar padded frames (f0h/f1h). MODE 1: direct fp32 frames.
template<int MODE>
__global__ __launch_bounds__(256) void interp_tv_kernel(
    const float* __restrict__ frames,
    const __half* __restrict__ f0h, const __half* __restrict__ f1h,
    const float* __restrict__ flow, const float* __restrict__ mask,
    float* __restrict__ stacked, float* __restrict__ tv_out)
{
    int bid = blockIdx.x;
    int wb  = (bid & 7) * (NPIX / 512 / 8) + (bid >> 3);  // image n -> XCD n
    int idx0 = wb * 512 + (int)threadIdx.x * 2;           // 2 adjacent px
    int w0 = idx0 & (WW - 1);
    int h  = (idx0 >> 9) & (HH - 1);
    int n  = idx0 >> 18;

    float4 fl = *reinterpret_cast<const float4*>(flow + (size_t)idx0 * 2);
    float2 mk = *reinterpret_cast<const float2*>(mask + idx0);

    float hhv = -1.0f + (float)h * (2.0f / 511.0f);
    float wv0 = -1.0f + (float)w0 * (2.0f / 511.0f);
    float wv1 = -1.0f + (float)(w0 + 1) * (2.0f / 511.0f);

    float o00[3], o01[3], o10[3], o11[3];
    if constexpr (MODE == 0) {
        const __half* i0 = f0h + (size_t)n * (HH * WW * 4);
        const __half* i1 = f1h + (size_t)n * (HH * WW * 4);
        bilerp_h(i0, hhv + fl.x * 0.5f, wv0 + fl.y * 0.5f, o00);
        bilerp_h(i1, hhv - fl.x * 0.5f, wv0 - fl.y * 0.5f, o01);
        bilerp_h(i0, hhv + fl.z * 0.5f, wv1 + fl.w * 0.5f, o10);
        bilerp_h(i1, hhv - fl.z * 0.5f, wv1 - fl.w * 0.5f, o11);
    } else {
        const float* img = frames + (size_t)n * (HH * WW * 6);
        bilerp_f(img + 0, hhv + fl.x * 0.5f, wv0 + fl.y * 0.5f, o00);
        bilerp_f(img + 3, hhv - fl.x * 0.5f, wv0 - fl.y * 0.5f, o01);
        bilerp_f(img + 0, hhv + fl.z * 0.5f, wv1 + fl.w * 0.5f, o10);
        bilerp_f(img + 3, hhv - fl.z * 0.5f, wv1 - fl.w * 0.5f, o11);
    }

    float m0 = 0.5f * (1.0f + mk.x), om0 = 1.0f - m0;
    float m1 = 0.5f * (1.0f + mk.y), om1 = 1.0f - m1;
    float2* sp = reinterpret_cast<float2*>(stacked + (size_t)idx0 * 3);
    sp[0] = make_float2(m0 * o00[0] + om0 * o01[0], m0 * o00[1] + om0 * o01[1]);
    sp[1] = make_float2(m0 * o00[2] + om0 * o01[2], m1 * o10[0] + om1 * o11[0]);
    sp[2] = make_float2(m1 * o10[1] + om1 * o11[1], m1 * o10[2] + om1 * o11[2]);

    // ---- TV (right diff for px0 is in-register) ----
    float tvf = fabsf(fl.z - fl.x) + fabsf(fl.w - fl.y);
    float tvm = fabsf(mk.y - mk.x);
    if (h < HH - 1) {
        float4 fld = *reinterpret_cast<const float4*>(flow + (size_t)(idx0 + WW) * 2);
        float2 mkd = *reinterpret_cast<const float2*>(mask + (idx0 + WW));
        tvf += fabsf(fld.x - fl.x) + fabsf(fld.y - fl.y)
             + fabsf(fld.z - fl.z) + fabsf(fld.w - fl.w);
        tvm += fabsf(mkd.x - mk.x) + fabsf(mkd.y - mk.y);
    }
    if (w0 < WW - 2) {
        float2 flr = *reinterpret_cast<const float2*>(flow + (size_t)(idx0 + 2) * 2);
        float  mkr = mask[idx0 + 2];
        tvf += fabsf(flr.x - fl.z) + fabsf(flr.y - fl.w);
        tvm += fabsf(mkr - mk.y);
    }
    float tv = GAMMA_FLOW * tvf + GAMMA_MASK * tvm;
#pragma unroll
    for (int off = 32; off > 0; off >>= 1) tv += __shfl_xor(tv, off);
    if ((threadIdx.x & 63) == 0) atomicAdd(tv_out, tv * INV_TOTAL);
}

extern "C" void kernel_launch(void* const* d_in, const int* in_sizes, int n_in,
                              void* d_out, int out_size, void* d_ws, size_t ws_size,
                              hipStream_t stream)
{
    const float* frames  = (const float*)d_in[0];
    const float* encoded = (const float*)d_in[1];
    const float* conv_w  = (const float*)d_in[2];
    const float* conv_b  = (const float*)d_in[3];

    float* out     = (float*)d_out;
    float* stacked = out;                       // NPIX*3
    float* flow    = out + (size_t)NPIX * 3;    // NPIX*2
    float* tv      = out + (size_t)NPIX * 5;    // 1

    hipMemsetAsync(tv, 0, sizeof(float), stream);

    const size_t frame_bytes = (size_t)NPIX * 4 * sizeof(__half); // 16 MiB each
    const size_t need = 2 * frame_bytes + (size_t)NPIX * sizeof(float);

    if (ws_size >= need) {
        __half* f0h = (__half*)d_ws;
        __half* f1h = (__half*)((char*)d_ws + frame_bytes);
        float*  mask = (float*)((char*)d_ws + 2 * frame_bytes);

        cvt_kernel<<<NPIX / 256, 256, 0, stream>>>(frames, f0h, f1h);
        conv_tanh_kernel<<<NPIX / 128, 256, 0, stream>>>(encoded, conv_w, conv_b,
                                                         flow, mask);
        interp_tv_kernel<0><<<NPIX / 512, 256, 0, stream>>>(
            frames, f0h, f1h, flow, mask, stacked, tv);
    } else {
        float* mask = (float*)d_ws;
        conv_tanh_kernel<<<NPIX / 128, 256, 0, stream>>>(encoded, conv_w, conv_b,
                                                         flow, mask);
        interp_tv_kernel<1><<<NPIX / 512, 256, 0, stream>>>(
            frames, (const __half*)nullptr, (const __half*)nullptr,
            flow, mask, stacked, tv);
    }
}